// Round 2
// baseline (536.395 us; speedup 1.0000x reference)
//
#include <hip/hip_runtime.h>
#include <cstdint>
#include <cstddef>

typedef short bf16x8 __attribute__((ext_vector_type(8)));
typedef float f32x4 __attribute__((ext_vector_type(4)));

// ---- problem constants ----
// B=8, H=W=128, C=256, heads=8, hd=32, ws=8, shift=4, N=64 tokens/window,
// 16x16 windows/image, 2048 windows total.

// ---- workspace layout (byte offsets) ----
#define WS_QKVW   0u          // bf16 [768][256]
#define WS_PROJW  393216u     // bf16 [256][256]
#define WS_QKVB   524288u     // f32  [768]  (q_bias, 0, v_bias)
#define WS_SCALE  527360u     // f32  [8]    exp(min(logit_scale, ln 100))
#define WS_BT     527392u     // f32  [225][8] cpb table
#define WS_BIAS   534592u     // f32  [8][jt4][it4][lane64][r4]  (S^T C-frag swizzled)
// total needed: 665664 bytes

// ---- LDS layout (ushort units) ----  69 KB -> 2 blocks/CU
#define XS_US   0          // bf16 [64][264]  x-window; later attn_out (reused)
#define VT_US   16896      // per head 2304 us: v^T [32][72]
#define SMEM_US 35328
#define SMEM_BYTES (SMEM_US * 2)   // 70656 bytes

__device__ __forceinline__ unsigned short f2b(float f) {
  union { float f; unsigned int u; } v; v.f = f;
  return (unsigned short)((v.u + 0x7FFFu + ((v.u >> 16) & 1u)) >> 16);
}
__device__ __forceinline__ int pack2(float a, float b) {
  return (int)(((unsigned)f2b(b) << 16) | (unsigned)f2b(a));
}

// ---------------- prep kernels ----------------

__global__ void prep_weights(const float* __restrict__ qkv_w,
                             const float* __restrict__ q_bias,
                             const float* __restrict__ v_bias,
                             const float* __restrict__ logit_scale,
                             const float* __restrict__ proj_w,
                             unsigned char* __restrict__ ws) {
  int gid = blockIdx.x * 256 + threadIdx.x;            // 0 .. 196607
  unsigned short* qw = (unsigned short*)(ws + WS_QKVW);
  unsigned short* pw = (unsigned short*)(ws + WS_PROJW);
  if (gid < 196608) qw[gid] = f2b(qkv_w[gid]);
  if (gid < 65536)  pw[gid] = f2b(proj_w[gid]);
  if (gid < 768) {
    float v = 0.f;
    if (gid < 256) v = q_bias[gid];
    else if (gid >= 512) v = v_bias[gid - 512];
    ((float*)(ws + WS_QKVB))[gid] = v;
  }
  if (gid < 8) {
    float ls = logit_scale[gid];
    ((float*)(ws + WS_SCALE))[gid] = __expf(fminf(ls, 4.605170185988091f));
  }
}

__global__ void prep_cpb(const float* __restrict__ w1, const float* __restrict__ b1,
                         const float* __restrict__ w2, unsigned char* __restrict__ ws) {
  __shared__ float hid[512];
  const int r = blockIdx.x;            // 0..224
  const int dh = r / 15, dw = r % 15;
  float t0 = ((float)(dh - 7)) / 7.0f * 8.0f;
  float t1 = ((float)(dw - 7)) / 7.0f * 8.0f;
  float a0 = log2f(fabsf(t0) + 1.0f) / 3.0f;
  float a1 = log2f(fabsf(t1) + 1.0f) / 3.0f;
  t0 = (t0 < 0.f) ? -a0 : a0;
  t1 = (t1 < 0.f) ? -a1 : a1;
  const int j = threadIdx.x;           // 0..511
  float h = t0 * w1[2 * j] + t1 * w1[2 * j + 1] + b1[j];
  hid[j] = fmaxf(h, 0.f);
  __syncthreads();
  const int wave = j >> 6, lane = j & 63;   // wave == head
  float p = 0.f;
  for (int jj = lane; jj < 512; jj += 64) p += hid[jj] * w2[wave * 512 + jj];
  #pragma unroll
  for (int off = 32; off > 0; off >>= 1) p += __shfl_down(p, off, 64);
  if (lane == 0) ((float*)(ws + WS_BT))[r * 8 + wave] = p;
}

// bias pre-swizzled for the TRANSPOSED score layout:
// S^T C-frag: i (query) = it*16 + (lane&15), j (key) = jt*16 + (lane>>4)*4 + r
__global__ void prep_bias(unsigned char* __restrict__ ws) {
  int u = blockIdx.x * 256 + threadIdx.x;   // 0..32767
  int r = u & 3;
  int lane = (u >> 2) & 63;
  int it = (u >> 8) & 3;
  int jt = (u >> 10) & 3;
  int h = (u >> 12);
  int i = it * 16 + (lane & 15);
  int j = jt * 16 + (lane >> 4) * 4 + r;
  int idx = ((i >> 3) - (j >> 3) + 7) * 15 + ((i & 7) - (j & 7) + 7);
  float xv = ((const float*)(ws + WS_BT))[idx * 8 + h];
  ((float*)(ws + WS_BIAS))[u] = 16.0f / (1.0f + __expf(-xv));
}

// ---------------- main fused kernel ----------------

__launch_bounds__(512, 4)
__global__ void swin_main(const float* __restrict__ x,
                          const unsigned char* __restrict__ ws,
                          float* __restrict__ out,
                          const float* __restrict__ proj_b) {
  extern __shared__ unsigned short sm[];
  const int tid = threadIdx.x;
  const int wave = tid >> 6;      // == head
  const int lane = tid & 63;
  const int quad = lane >> 4;
  const int l15 = lane & 15;

  const int blk = blockIdx.x;
  const int b = blk >> 8;
  const int win = blk & 255;
  const int wr = win >> 4;
  const int wc = win & 15;

  const unsigned short* qkvw = (const unsigned short*)(ws + WS_QKVW);
  const unsigned short* projw = (const unsigned short*)(ws + WS_PROJW);
  const float* qkvb = (const float*)(ws + WS_QKVB);
  const float* scales = (const float*)(ws + WS_SCALE);
  const float* bias_sw = (const float*)(ws + WS_BIAS);

  // ---- phase 0: gather shifted window -> xs bf16 [64][264]
  {
    const int t = tid >> 3;          // token 0..63
    const int cg = tid & 7;          // channel group
    const int rw = t >> 3, cw = t & 7;
    const int gr = (wr * 8 + rw + 4) & 127;
    const int gc = (wc * 8 + cw + 4) & 127;
    const float* src = x + ((size_t)b * 16384 + gr * 128 + gc) * 256 + cg * 32;
    unsigned short* dst = sm + XS_US + t * 264 + cg * 32;
    #pragma unroll
    for (int kk = 0; kk < 4; ++kk) {
      f32x4 a = *(const f32x4*)(src + kk * 8);
      f32x4 c = *(const f32x4*)(src + kk * 8 + 4);
      union { bf16x8 v; unsigned short u[8]; } pk;
      #pragma unroll
      for (int e = 0; e < 4; ++e) { pk.u[e] = f2b(a[e]); pk.u[4 + e] = f2b(c[e]); }
      *(bf16x8*)(dst + kk * 8) = pk.v;
    }
  }
  __syncthreads();

  const int h = wave;

  // ---- pass A: q^T, k^T via swapped MFMA (A = W rows, B = x token rows)
  // C-frag: col = token (l15), row = channel (quad*4+r); tiles: ct(chan) x tt(tok)
  f32x4 aQ[2][4], aK[2][4];
  #pragma unroll
  for (int ct = 0; ct < 2; ++ct)
    #pragma unroll
    for (int tt = 0; tt < 4; ++tt) { aQ[ct][tt] = f32x4{0,0,0,0}; aK[ct][tt] = f32x4{0,0,0,0}; }
  for (int k0 = 0; k0 < 256; k0 += 32) {
    bf16x8 xfr[4];
    #pragma unroll
    for (int tt = 0; tt < 4; ++tt)
      xfr[tt] = *(const bf16x8*)(sm + XS_US + (tt * 16 + l15) * 264 + k0 + quad * 8);
    bf16x8 wq[2], wk[2];
    #pragma unroll
    for (int ct = 0; ct < 2; ++ct) {
      wq[ct] = *(const bf16x8*)(qkvw + (h * 32 + ct * 16 + l15) * 256 + k0 + quad * 8);
      wk[ct] = *(const bf16x8*)(qkvw + (256 + h * 32 + ct * 16 + l15) * 256 + k0 + quad * 8);
    }
    #pragma unroll
    for (int ct = 0; ct < 2; ++ct)
      #pragma unroll
      for (int tt = 0; tt < 4; ++tt) {
        aQ[ct][tt] = __builtin_amdgcn_mfma_f32_16x16x32_bf16(wq[ct], xfr[tt], aQ[ct][tt], 0, 0, 0);
        aK[ct][tt] = __builtin_amdgcn_mfma_f32_16x16x32_bf16(wk[ct], xfr[tt], aK[ct][tt], 0, 0, 0);
      }
  }
  // q bias (k has none), cosine norms per token (token = tt*16+l15)
  #pragma unroll
  for (int ct = 0; ct < 2; ++ct)
    #pragma unroll
    for (int r = 0; r < 4; ++r) {
      const float qb = qkvb[h * 32 + ct * 16 + quad * 4 + r];
      #pragma unroll
      for (int tt = 0; tt < 4; ++tt) aQ[ct][tt][r] += qb;
    }
  const float sc = scales[h];
  int aqi[4][4], bki[4][4];
  #pragma unroll
  for (int tt = 0; tt < 4; ++tt) {
    float ssq = 0.f, ssk = 0.f;
    #pragma unroll
    for (int ct = 0; ct < 2; ++ct)
      #pragma unroll
      for (int r = 0; r < 4; ++r) {
        ssq += aQ[ct][tt][r] * aQ[ct][tt][r];
        ssk += aK[ct][tt][r] * aK[ct][tt][r];
      }
    ssq += __shfl_xor(ssq, 16, 64); ssq += __shfl_xor(ssq, 32, 64);
    ssk += __shfl_xor(ssk, 16, 64); ssk += __shfl_xor(ssk, 32, 64);
    const float invq = sc / fmaxf(sqrtf(ssq), 1e-12f);
    const float invk = 1.0f / fmaxf(sqrtf(ssk), 1e-12f);
    int qp[2][2], kp[2][2];
    #pragma unroll
    for (int ct = 0; ct < 2; ++ct) {
      qp[ct][0] = pack2(aQ[ct][tt][0] * invq, aQ[ct][tt][1] * invq);
      qp[ct][1] = pack2(aQ[ct][tt][2] * invq, aQ[ct][tt][3] * invq);
      kp[ct][0] = pack2(aK[ct][tt][0] * invk, aK[ct][tt][1] * invk);
      kp[ct][1] = pack2(aK[ct][tt][2] * invk, aK[ct][tt][3] * invk);
    }
    // cross-quad shuffle: C-frag (chan on quad*4+r) -> op-frag (chan on quad*8+e)
    #pragma unroll
    for (int di = 0; di < 4; ++di) {
      const int srcl = ((quad & 1) * 2 + (di >> 1)) * 16 + l15;
      int a0 = __shfl(qp[0][di & 1], srcl, 64);
      int a1 = __shfl(qp[1][di & 1], srcl, 64);
      aqi[tt][di] = (quad >= 2) ? a1 : a0;
      int b0 = __shfl(kp[0][di & 1], srcl, 64);
      int b1 = __shfl(kp[1][di & 1], srcl, 64);
      bki[tt][di] = (quad >= 2) ? b1 : b0;
    }
  }

  // ---- pass B: v (normal orientation) -> v^T in wave-private LDS
  {
    f32x4 aV[4][2];
    #pragma unroll
    for (int mt = 0; mt < 4; ++mt)
      #pragma unroll
      for (int nt = 0; nt < 2; ++nt) aV[mt][nt] = f32x4{0,0,0,0};
    for (int k0 = 0; k0 < 256; k0 += 32) {
      bf16x8 xfr[4];
      #pragma unroll
      for (int mt = 0; mt < 4; ++mt)
        xfr[mt] = *(const bf16x8*)(sm + XS_US + (mt * 16 + l15) * 264 + k0 + quad * 8);
      #pragma unroll
      for (int nt = 0; nt < 2; ++nt) {
        bf16x8 wv = *(const bf16x8*)(qkvw + (512 + h * 32 + nt * 16 + l15) * 256 + k0 + quad * 8);
        #pragma unroll
        for (int mt = 0; mt < 4; ++mt)
          aV[mt][nt] = __builtin_amdgcn_mfma_f32_16x16x32_bf16(xfr[mt], wv, aV[mt][nt], 0, 0, 0);
      }
    }
    #pragma unroll
    for (int nt = 0; nt < 2; ++nt) {
      const float vb = qkvb[512 + h * 32 + nt * 16 + l15];
      #pragma unroll
      for (int mt = 0; mt < 4; ++mt) {
        int w0 = pack2(aV[mt][nt][0] + vb, aV[mt][nt][1] + vb);
        int w1 = pack2(aV[mt][nt][2] + vb, aV[mt][nt][3] + vb);
        // v^T[chan][token], chan = nt*16+l15, tokens mt*16+quad*4 .. +3
        int2* dst = (int2*)(sm + VT_US + h * 2304 + (nt * 16 + l15) * 72 + mt * 16 + quad * 4);
        *dst = int2{w0, w1};
      }
    }
  }

  // ---- scores: S^T = K . Q^T  (C-frag: col = i on l15, row = j on quad*4+r)
  union { int i[4]; bf16x8 v; } fa, fb;
  f32x4 S[4][4];
  {
    bf16x8 aq[4], bk[4];
    #pragma unroll
    for (int tt = 0; tt < 4; ++tt) {
      #pragma unroll
      for (int di = 0; di < 4; ++di) { fa.i[di] = aqi[tt][di]; fb.i[di] = bki[tt][di]; }
      aq[tt] = fa.v; bk[tt] = fb.v;
    }
    #pragma unroll
    for (int jt = 0; jt < 4; ++jt)
      #pragma unroll
      for (int it = 0; it < 4; ++it)
        S[jt][it] = __builtin_amdgcn_mfma_f32_16x16x32_bf16(bk[jt], aq[it], f32x4{0,0,0,0}, 0, 0, 0);
  }
  // + relative-position bias (pre-swizzled) and shift mask
  {
    const bool has_mask = (wr == 15) || (wc == 15);
    #pragma unroll
    for (int jt = 0; jt < 4; ++jt)
      #pragma unroll
      for (int it = 0; it < 4; ++it) {
        f32x4 bv = *(const f32x4*)(bias_sw + (size_t)(((h * 4 + jt) * 4 + it) * 64 + lane) * 4);
        #pragma unroll
        for (int r = 0; r < 4; ++r) S[jt][it][r] += bv[r];
        if (has_mask) {
          const int i = it * 16 + l15;
          const int bri = (wr == 15) ? (((i >> 3) < 4) ? 1 : 2) : 0;
          const int bci = (wc == 15) ? (((i & 7) < 4) ? 1 : 2) : 0;
          #pragma unroll
          for (int r = 0; r < 4; ++r) {
            const int j = jt * 16 + quad * 4 + r;
            const int brj = (wr == 15) ? (((j >> 3) < 4) ? 1 : 2) : 0;
            const int bcj = (wc == 15) ? (((j & 7) < 4) ? 1 : 2) : 0;
            if (bri != brj || bci != bcj) S[jt][it][r] -= 100.0f;
          }
        }
      }
  }
  // ---- softmax over j (in-lane 16 + 2 cross-quad shuffles), P normalized at pack
  int api[4][2][4];
  {
    #pragma unroll
    for (int it = 0; it < 4; ++it) {
      float m = -1e30f;
      #pragma unroll
      for (int jt = 0; jt < 4; ++jt)
        #pragma unroll
        for (int r = 0; r < 4; ++r) m = fmaxf(m, S[jt][it][r]);
      m = fmaxf(m, __shfl_xor(m, 16, 64));
      m = fmaxf(m, __shfl_xor(m, 32, 64));
      float sum = 0.f;
      #pragma unroll
      for (int jt = 0; jt < 4; ++jt)
        #pragma unroll
        for (int r = 0; r < 4; ++r) { float p = __expf(S[jt][it][r] - m); S[jt][it][r] = p; sum += p; }
      sum += __shfl_xor(sum, 16, 64);
      sum += __shfl_xor(sum, 32, 64);
      const float rinv = 1.0f / sum;
      int sp[4][2];
      #pragma unroll
      for (int jt = 0; jt < 4; ++jt) {
        sp[jt][0] = pack2(S[jt][it][0] * rinv, S[jt][it][1] * rinv);
        sp[jt][1] = pack2(S[jt][it][2] * rinv, S[jt][it][3] * rinv);
      }
      #pragma unroll
      for (int ks = 0; ks < 2; ++ks)
        #pragma unroll
        for (int di = 0; di < 4; ++di) {
          const int srcl = ((quad & 1) * 2 + (di >> 1)) * 16 + l15;
          int c0 = __shfl(sp[ks * 2][di & 1], srcl, 64);
          int c1 = __shfl(sp[ks * 2 + 1][di & 1], srcl, 64);
          api[it][ks][di] = (quad >= 2) ? c1 : c0;
        }
    }
  }
  // all xs reads are done in pass A/B; fence before overwriting xs with O
  __syncthreads();

  // ---- PV: O = P . V  (A = P^T-frag, B = v^T rows from LDS)
  {
    f32x4 aO[4][2];
    #pragma unroll
    for (int it = 0; it < 4; ++it)
      #pragma unroll
      for (int c2 = 0; c2 < 2; ++c2) aO[it][c2] = f32x4{0,0,0,0};
    #pragma unroll
    for (int ks = 0; ks < 2; ++ks) {
      bf16x8 vfr[2];
      #pragma unroll
      for (int c2 = 0; c2 < 2; ++c2)
        vfr[c2] = *(const bf16x8*)(sm + VT_US + h * 2304 + (c2 * 16 + l15) * 72 + ks * 32 + quad * 8);
      #pragma unroll
      for (int it = 0; it < 4; ++it) {
        #pragma unroll
        for (int di = 0; di < 4; ++di) fa.i[di] = api[it][ks][di];
        #pragma unroll
        for (int c2 = 0; c2 < 2; ++c2)
          aO[it][c2] = __builtin_amdgcn_mfma_f32_16x16x32_bf16(fa.v, vfr[c2], aO[it][c2], 0, 0, 0);
      }
    }
    // O -> xs overlay [tok][264], cols h*32..h*32+31
    #pragma unroll
    for (int it = 0; it < 4; ++it)
      #pragma unroll
      for (int c2 = 0; c2 < 2; ++c2)
        #pragma unroll
        for (int r = 0; r < 4; ++r) {
          const int tok = it * 16 + quad * 4 + r;
          sm[XS_US + tok * 264 + h * 32 + c2 * 16 + l15] = f2b(aO[it][c2][r]);
        }
  }
  __syncthreads();

  // ---- proj GEMM (64x256 = attn_out @ Wp^T) + unshift scatter-store
  {
    f32x4 acc[4][2];
    #pragma unroll
    for (int mt = 0; mt < 4; ++mt)
      #pragma unroll
      for (int nt = 0; nt < 2; ++nt) acc[mt][nt] = f32x4{0,0,0,0};
    const int ncol0 = wave * 32;
    for (int k0 = 0; k0 < 256; k0 += 32) {
      bf16x8 afr[4];
      #pragma unroll
      for (int mt = 0; mt < 4; ++mt)
        afr[mt] = *(const bf16x8*)(sm + XS_US + (mt * 16 + l15) * 264 + k0 + quad * 8);
      #pragma unroll
      for (int nt = 0; nt < 2; ++nt) {
        bf16x8 bfr = *(const bf16x8*)(projw + (ncol0 + nt * 16 + l15) * 256 + k0 + quad * 8);
        #pragma unroll
        for (int mt = 0; mt < 4; ++mt)
          acc[mt][nt] = __builtin_amdgcn_mfma_f32_16x16x32_bf16(afr[mt], bfr, acc[mt][nt], 0, 0, 0);
      }
    }
    #pragma unroll
    for (int nt = 0; nt < 2; ++nt) {
      const int col = ncol0 + nt * 16 + l15;
      const float pb = proj_b[col];
      #pragma unroll
      for (int mt = 0; mt < 4; ++mt) {
        #pragma unroll
        for (int r = 0; r < 4; ++r) {
          const int tok = mt * 16 + quad * 4 + r;
          const int rw = tok >> 3, cw = tok & 7;
          const int gr = (wr * 8 + rw + 4) & 127;
          const int gc = (wc * 8 + cw + 4) & 127;
          out[((size_t)b * 16384 + gr * 128 + gc) * 256 + col] = acc[mt][nt][r] + pb;
        }
      }
    }
  }
}

// ---------------- launch ----------------

extern "C" void kernel_launch(void* const* d_in, const int* in_sizes, int n_in,
                              void* d_out, int out_size, void* d_ws, size_t ws_size,
                              hipStream_t stream) {
  const float* x           = (const float*)d_in[0];
  const float* qkv_w       = (const float*)d_in[1];
  const float* q_bias      = (const float*)d_in[2];
  const float* v_bias      = (const float*)d_in[3];
  const float* logit_scale = (const float*)d_in[4];
  const float* cpb_w1      = (const float*)d_in[5];
  const float* cpb_b1      = (const float*)d_in[6];
  const float* cpb_w2      = (const float*)d_in[7];
  const float* proj_w      = (const float*)d_in[8];
  const float* proj_b      = (const float*)d_in[9];
  unsigned char* ws = (unsigned char*)d_ws;
  float* out = (float*)d_out;

  prep_weights<<<768, 256, 0, stream>>>(qkv_w, q_bias, v_bias, logit_scale, proj_w, ws);
  prep_cpb<<<225, 512, 0, stream>>>(cpb_w1, cpb_b1, cpb_w2, ws);
  prep_bias<<<128, 256, 0, stream>>>(ws);

  (void)hipFuncSetAttribute((const void*)swin_main,
                            hipFuncAttributeMaxDynamicSharedMemorySize, SMEM_BYTES);
  swin_main<<<2048, 512, SMEM_BYTES, stream>>>(x, ws, out, proj_b);
}

// Round 3
// 531.714 us; speedup vs baseline: 1.0088x; 1.0088x over previous
//
#include <hip/hip_runtime.h>
#include <cstdint>
#include <cstddef>

typedef short bf16x8 __attribute__((ext_vector_type(8)));
typedef float f32x4 __attribute__((ext_vector_type(4)));

// ---- problem constants ----
// B=8, H=W=128, C=256, heads=8, hd=32, ws=8, shift=4, N=64 tokens/window,
// 16x16 windows/image, 2048 windows total.

// ---- workspace layout (byte offsets) ----
#define WS_QKVW   0u          // bf16 [768][256]
#define WS_PROJW  393216u     // bf16 [256][256]
#define WS_QKVB   524288u     // f32  [768]  (q_bias, 0, v_bias)
#define WS_SCALE  527360u     // f32  [8]    exp(min(logit_scale, ln 100))
#define WS_BT     527392u     // f32  [225][8] cpb table
#define WS_BIAS   534592u     // f32  [8][jt4][it4][lane64][r4]  (S^T C-frag swizzled)
// total needed: 665664 bytes

// ---- LDS layout (ushort units) ----  33.8 KB -> 2 blocks/CU (reg-capped)
#define XS_US   0          // bf16 [64][264]  x-window; later attn_out (reused)
#define SMEM_US 16896
#define SMEM_BYTES (SMEM_US * 2)   // 33792 bytes

__device__ __forceinline__ unsigned short f2b(float f) {
  union { float f; unsigned int u; } v; v.f = f;
  return (unsigned short)((v.u + 0x7FFFu + ((v.u >> 16) & 1u)) >> 16);
}
__device__ __forceinline__ int pack2(float a, float b) {
  return (int)(((unsigned)f2b(b) << 16) | (unsigned)f2b(a));
}

// ---------------- prep kernels ----------------

__global__ void prep_weights(const float* __restrict__ qkv_w,
                             const float* __restrict__ q_bias,
                             const float* __restrict__ v_bias,
                             const float* __restrict__ logit_scale,
                             const float* __restrict__ proj_w,
                             unsigned char* __restrict__ ws) {
  int gid = blockIdx.x * 256 + threadIdx.x;            // 0 .. 196607
  unsigned short* qw = (unsigned short*)(ws + WS_QKVW);
  unsigned short* pw = (unsigned short*)(ws + WS_PROJW);
  if (gid < 196608) qw[gid] = f2b(qkv_w[gid]);
  if (gid < 65536)  pw[gid] = f2b(proj_w[gid]);
  if (gid < 768) {
    float v = 0.f;
    if (gid < 256) v = q_bias[gid];
    else if (gid >= 512) v = v_bias[gid - 512];
    ((float*)(ws + WS_QKVB))[gid] = v;
  }
  if (gid < 8) {
    float ls = logit_scale[gid];
    ((float*)(ws + WS_SCALE))[gid] = __expf(fminf(ls, 4.605170185988091f));
  }
}

__global__ void prep_cpb(const float* __restrict__ w1, const float* __restrict__ b1,
                         const float* __restrict__ w2, unsigned char* __restrict__ ws) {
  __shared__ float hid[512];
  const int r = blockIdx.x;            // 0..224
  const int dh = r / 15, dw = r % 15;
  float t0 = ((float)(dh - 7)) / 7.0f * 8.0f;
  float t1 = ((float)(dw - 7)) / 7.0f * 8.0f;
  float a0 = log2f(fabsf(t0) + 1.0f) / 3.0f;
  float a1 = log2f(fabsf(t1) + 1.0f) / 3.0f;
  t0 = (t0 < 0.f) ? -a0 : a0;
  t1 = (t1 < 0.f) ? -a1 : a1;
  const int j = threadIdx.x;           // 0..511
  float h = t0 * w1[2 * j] + t1 * w1[2 * j + 1] + b1[j];
  hid[j] = fmaxf(h, 0.f);
  __syncthreads();
  const int wave = j >> 6, lane = j & 63;   // wave == head
  float p = 0.f;
  for (int jj = lane; jj < 512; jj += 64) p += hid[jj] * w2[wave * 512 + jj];
  #pragma unroll
  for (int off = 32; off > 0; off >>= 1) p += __shfl_down(p, off, 64);
  if (lane == 0) ((float*)(ws + WS_BT))[r * 8 + wave] = p;
}

// bias pre-swizzled for the TRANSPOSED score layout:
// S^T C-frag: i (query) = it*16 + (lane&15), j (key) = jt*16 + (lane>>4)*4 + r
__global__ void prep_bias(unsigned char* __restrict__ ws) {
  int u = blockIdx.x * 256 + threadIdx.x;   // 0..32767
  int r = u & 3;
  int lane = (u >> 2) & 63;
  int it = (u >> 8) & 3;
  int jt = (u >> 10) & 3;
  int h = (u >> 12);
  int i = it * 16 + (lane & 15);
  int j = jt * 16 + (lane >> 4) * 4 + r;
  int idx = ((i >> 3) - (j >> 3) + 7) * 15 + ((i & 7) - (j & 7) + 7);
  float xv = ((const float*)(ws + WS_BT))[idx * 8 + h];
  ((float*)(ws + WS_BIAS))[u] = 16.0f / (1.0f + __expf(-xv));
}

// ---------------- main fused kernel ----------------

__launch_bounds__(512, 4)
__global__ void swin_main(const float* __restrict__ x,
                          const unsigned char* __restrict__ ws,
                          float* __restrict__ out,
                          const float* __restrict__ proj_b) {
  extern __shared__ unsigned short sm[];
  const int tid = threadIdx.x;
  const int wave = tid >> 6;      // == head
  const int lane = tid & 63;
  const int quad = lane >> 4;
  const int l15 = lane & 15;

  const int blk = blockIdx.x;
  const int b = blk >> 8;
  const int win = blk & 255;
  const int wr = win >> 4;
  const int wc = win & 15;

  const unsigned short* qkvw = (const unsigned short*)(ws + WS_QKVW);
  const unsigned short* projw = (const unsigned short*)(ws + WS_PROJW);
  const float* qkvb = (const float*)(ws + WS_QKVB);
  const float* scales = (const float*)(ws + WS_SCALE);
  const float* bias_sw = (const float*)(ws + WS_BIAS);

  // ---- phase 0: gather shifted window -> xs bf16 [64][264]
  {
    const int t = tid >> 3;          // token 0..63
    const int cg = tid & 7;          // channel group
    const int rw = t >> 3, cw = t & 7;
    const int gr = (wr * 8 + rw + 4) & 127;
    const int gc = (wc * 8 + cw + 4) & 127;
    const float* src = x + ((size_t)b * 16384 + gr * 128 + gc) * 256 + cg * 32;
    unsigned short* dst = sm + XS_US + t * 264 + cg * 32;
    #pragma unroll
    for (int kk = 0; kk < 4; ++kk) {
      f32x4 a = *(const f32x4*)(src + kk * 8);
      f32x4 c = *(const f32x4*)(src + kk * 8 + 4);
      union { bf16x8 v; unsigned short u[8]; } pk;
      #pragma unroll
      for (int e = 0; e < 4; ++e) { pk.u[e] = f2b(a[e]); pk.u[4 + e] = f2b(c[e]); }
      *(bf16x8*)(dst + kk * 8) = pk.v;
    }
  }
  __syncthreads();

  const int h = wave;
  union U8 { int i[4]; bf16x8 v; };

  bf16x8 vf[2][2];   // PV B-frags: [c2 chan tile][ks]  (chan=c2*16+l15, k-tok=ks*32+quad*8+e)
  bf16x8 aq[4];      // S^T B-frags: [it] (tok=it*16+l15, k-chan=quad*8+e), q normalized*scale
  bf16x8 bk[4];      // S^T A-frags: [jt] (tok=jt*16+l15, k-chan=quad*8+e), k normalized

  // ---- pass V: v = xs @ Wv^T (normal orientation) -> reg B-frags via cross-quad shuffle
  {
    f32x4 aV[4][2];
    #pragma unroll
    for (int mt = 0; mt < 4; ++mt)
      #pragma unroll
      for (int nt = 0; nt < 2; ++nt) aV[mt][nt] = f32x4{0,0,0,0};
    for (int k0 = 0; k0 < 256; k0 += 32) {
      bf16x8 xfr[4];
      #pragma unroll
      for (int mt = 0; mt < 4; ++mt)
        xfr[mt] = *(const bf16x8*)(sm + XS_US + (mt * 16 + l15) * 264 + k0 + quad * 8);
      #pragma unroll
      for (int nt = 0; nt < 2; ++nt) {
        bf16x8 wv = *(const bf16x8*)(qkvw + (512 + h * 32 + nt * 16 + l15) * 256 + k0 + quad * 8);
        #pragma unroll
        for (int mt = 0; mt < 4; ++mt)
          aV[mt][nt] = __builtin_amdgcn_mfma_f32_16x16x32_bf16(xfr[mt], wv, aV[mt][nt], 0, 0, 0);
      }
    }
    const float vb = qkvb[512 + h * 32 + l15];        // per c2 handled below
    #pragma unroll
    for (int c2 = 0; c2 < 2; ++c2) {
      const float vbc = qkvb[512 + h * 32 + c2 * 16 + l15];
      int vp[4][2];
      #pragma unroll
      for (int mt = 0; mt < 4; ++mt) {
        vp[mt][0] = pack2(aV[mt][c2][0] + vbc, aV[mt][c2][1] + vbc);
        vp[mt][1] = pack2(aV[mt][c2][2] + vbc, aV[mt][c2][3] + vbc);
      }
      #pragma unroll
      for (int ks = 0; ks < 2; ++ks) {
        U8 u;
        #pragma unroll
        for (int di = 0; di < 4; ++di) {
          const int srcl = ((quad & 1) * 2 + (di >> 1)) * 16 + l15;
          int c0 = __shfl(vp[ks * 2][di & 1], srcl, 64);
          int c1 = __shfl(vp[ks * 2 + 1][di & 1], srcl, 64);
          u.i[di] = (quad >= 2) ? c1 : c0;
        }
        vf[c2][ks] = u.v;
      }
    }
    (void)vb;
  }

  // ---- pass Q: q^T via swapped MFMA, normalize (scale folded), -> reg frags
  {
    f32x4 aQ[2][4];
    #pragma unroll
    for (int ct = 0; ct < 2; ++ct)
      #pragma unroll
      for (int tt = 0; tt < 4; ++tt) aQ[ct][tt] = f32x4{0,0,0,0};
    for (int k0 = 0; k0 < 256; k0 += 32) {
      bf16x8 xfr[4];
      #pragma unroll
      for (int tt = 0; tt < 4; ++tt)
        xfr[tt] = *(const bf16x8*)(sm + XS_US + (tt * 16 + l15) * 264 + k0 + quad * 8);
      #pragma unroll
      for (int ct = 0; ct < 2; ++ct) {
        bf16x8 wq = *(const bf16x8*)(qkvw + (h * 32 + ct * 16 + l15) * 256 + k0 + quad * 8);
        #pragma unroll
        for (int tt = 0; tt < 4; ++tt)
          aQ[ct][tt] = __builtin_amdgcn_mfma_f32_16x16x32_bf16(wq, xfr[tt], aQ[ct][tt], 0, 0, 0);
      }
    }
    #pragma unroll
    for (int ct = 0; ct < 2; ++ct)
      #pragma unroll
      for (int r = 0; r < 4; ++r) {
        const float qb = qkvb[h * 32 + ct * 16 + quad * 4 + r];
        #pragma unroll
        for (int tt = 0; tt < 4; ++tt) aQ[ct][tt][r] += qb;
      }
    const float sc = scales[h];
    #pragma unroll
    for (int tt = 0; tt < 4; ++tt) {
      float ssq = 0.f;
      #pragma unroll
      for (int ct = 0; ct < 2; ++ct)
        #pragma unroll
        for (int r = 0; r < 4; ++r) ssq += aQ[ct][tt][r] * aQ[ct][tt][r];
      ssq += __shfl_xor(ssq, 16, 64);
      ssq += __shfl_xor(ssq, 32, 64);
      const float invq = sc / fmaxf(sqrtf(ssq), 1e-12f);
      int qp[2][2];
      #pragma unroll
      for (int ct = 0; ct < 2; ++ct) {
        qp[ct][0] = pack2(aQ[ct][tt][0] * invq, aQ[ct][tt][1] * invq);
        qp[ct][1] = pack2(aQ[ct][tt][2] * invq, aQ[ct][tt][3] * invq);
      }
      U8 u;
      #pragma unroll
      for (int di = 0; di < 4; ++di) {
        const int srcl = ((quad & 1) * 2 + (di >> 1)) * 16 + l15;
        int a0 = __shfl(qp[0][di & 1], srcl, 64);
        int a1 = __shfl(qp[1][di & 1], srcl, 64);
        u.i[di] = (quad >= 2) ? a1 : a0;
      }
      aq[tt] = u.v;
    }
  }

  // ---- pass K: k^T via swapped MFMA, normalize -> reg frags
  {
    f32x4 aK[2][4];
    #pragma unroll
    for (int ct = 0; ct < 2; ++ct)
      #pragma unroll
      for (int tt = 0; tt < 4; ++tt) aK[ct][tt] = f32x4{0,0,0,0};
    for (int k0 = 0; k0 < 256; k0 += 32) {
      bf16x8 xfr[4];
      #pragma unroll
      for (int tt = 0; tt < 4; ++tt)
        xfr[tt] = *(const bf16x8*)(sm + XS_US + (tt * 16 + l15) * 264 + k0 + quad * 8);
      #pragma unroll
      for (int ct = 0; ct < 2; ++ct) {
        bf16x8 wk = *(const bf16x8*)(qkvw + (256 + h * 32 + ct * 16 + l15) * 256 + k0 + quad * 8);
        #pragma unroll
        for (int tt = 0; tt < 4; ++tt)
          aK[ct][tt] = __builtin_amdgcn_mfma_f32_16x16x32_bf16(wk, xfr[tt], aK[ct][tt], 0, 0, 0);
      }
    }
    #pragma unroll
    for (int tt = 0; tt < 4; ++tt) {
      float ssk = 0.f;
      #pragma unroll
      for (int ct = 0; ct < 2; ++ct)
        #pragma unroll
        for (int r = 0; r < 4; ++r) ssk += aK[ct][tt][r] * aK[ct][tt][r];
      ssk += __shfl_xor(ssk, 16, 64);
      ssk += __shfl_xor(ssk, 32, 64);
      const float invk = 1.0f / fmaxf(sqrtf(ssk), 1e-12f);
      int kp[2][2];
      #pragma unroll
      for (int ct = 0; ct < 2; ++ct) {
        kp[ct][0] = pack2(aK[ct][tt][0] * invk, aK[ct][tt][1] * invk);
        kp[ct][1] = pack2(aK[ct][tt][2] * invk, aK[ct][tt][3] * invk);
      }
      U8 u;
      #pragma unroll
      for (int di = 0; di < 4; ++di) {
        const int srcl = ((quad & 1) * 2 + (di >> 1)) * 16 + l15;
        int a0 = __shfl(kp[0][di & 1], srcl, 64);
        int a1 = __shfl(kp[1][di & 1], srcl, 64);
        u.i[di] = (quad >= 2) ? a1 : a0;
      }
      bk[tt] = u.v;
    }
  }

  // all xs reads done; fence before overwriting xs with O
  __syncthreads();

  // ---- attention, one query tile (it) at a time to bound register pressure
  const bool has_mask = (wr == 15) || (wc == 15);
  #pragma unroll 1
  for (int it = 0; it < 4; ++it) {
    f32x4 S[4];
    #pragma unroll
    for (int jt = 0; jt < 4; ++jt)
      S[jt] = __builtin_amdgcn_mfma_f32_16x16x32_bf16(bk[jt], aq[it], f32x4{0,0,0,0}, 0, 0, 0);
    #pragma unroll
    for (int jt = 0; jt < 4; ++jt) {
      f32x4 bv = *(const f32x4*)(bias_sw + (size_t)(((h * 4 + jt) * 4 + it) * 64 + lane) * 4);
      #pragma unroll
      for (int r = 0; r < 4; ++r) S[jt][r] += bv[r];
    }
    if (has_mask) {
      const int i = it * 16 + l15;
      const int bri = (wr == 15) ? (((i >> 3) < 4) ? 1 : 2) : 0;
      const int bci = (wc == 15) ? (((i & 7) < 4) ? 1 : 2) : 0;
      #pragma unroll
      for (int jt = 0; jt < 4; ++jt)
        #pragma unroll
        for (int r = 0; r < 4; ++r) {
          const int j = jt * 16 + quad * 4 + r;
          const int brj = (wr == 15) ? (((j >> 3) < 4) ? 1 : 2) : 0;
          const int bcj = (wc == 15) ? (((j & 7) < 4) ? 1 : 2) : 0;
          if (bri != brj || bci != bcj) S[jt][r] -= 100.0f;
        }
    }
    // softmax over j (16 in-lane + cross-quad)
    float m = -1e30f;
    #pragma unroll
    for (int jt = 0; jt < 4; ++jt)
      #pragma unroll
      for (int r = 0; r < 4; ++r) m = fmaxf(m, S[jt][r]);
    m = fmaxf(m, __shfl_xor(m, 16, 64));
    m = fmaxf(m, __shfl_xor(m, 32, 64));
    float sum = 0.f;
    #pragma unroll
    for (int jt = 0; jt < 4; ++jt)
      #pragma unroll
      for (int r = 0; r < 4; ++r) { float p = __expf(S[jt][r] - m); S[jt][r] = p; sum += p; }
    sum += __shfl_xor(sum, 16, 64);
    sum += __shfl_xor(sum, 32, 64);
    const float rinv = 1.0f / sum;
    int sp[4][2];
    #pragma unroll
    for (int jt = 0; jt < 4; ++jt) {
      sp[jt][0] = pack2(S[jt][0] * rinv, S[jt][1] * rinv);
      sp[jt][1] = pack2(S[jt][2] * rinv, S[jt][3] * rinv);
    }
    // convert to P A-frags and do PV immediately
    f32x4 aO[2];
    aO[0] = f32x4{0,0,0,0}; aO[1] = f32x4{0,0,0,0};
    #pragma unroll
    for (int ks = 0; ks < 2; ++ks) {
      U8 u;
      #pragma unroll
      for (int di = 0; di < 4; ++di) {
        const int srcl = ((quad & 1) * 2 + (di >> 1)) * 16 + l15;
        int c0 = __shfl(sp[ks * 2][di & 1], srcl, 64);
        int c1 = __shfl(sp[ks * 2 + 1][di & 1], srcl, 64);
        u.i[di] = (quad >= 2) ? c1 : c0;
      }
      #pragma unroll
      for (int c2 = 0; c2 < 2; ++c2)
        aO[c2] = __builtin_amdgcn_mfma_f32_16x16x32_bf16(u.v, vf[c2][ks], aO[c2], 0, 0, 0);
    }
    // O tile -> xs overlay [tok][264], cols h*32..h*32+31
    #pragma unroll
    for (int c2 = 0; c2 < 2; ++c2)
      #pragma unroll
      for (int r = 0; r < 4; ++r) {
        const int tok = it * 16 + quad * 4 + r;
        sm[XS_US + tok * 264 + h * 32 + c2 * 16 + l15] = f2b(aO[c2][r]);
      }
  }
  __syncthreads();

  // ---- proj GEMM (64x256 = attn_out @ Wp^T) + unshift scatter-store
  {
    f32x4 acc[4][2];
    #pragma unroll
    for (int mt = 0; mt < 4; ++mt)
      #pragma unroll
      for (int nt = 0; nt < 2; ++nt) acc[mt][nt] = f32x4{0,0,0,0};
    const int ncol0 = wave * 32;
    for (int k0 = 0; k0 < 256; k0 += 32) {
      bf16x8 afr[4];
      #pragma unroll
      for (int mt = 0; mt < 4; ++mt)
        afr[mt] = *(const bf16x8*)(sm + XS_US + (mt * 16 + l15) * 264 + k0 + quad * 8);
      #pragma unroll
      for (int nt = 0; nt < 2; ++nt) {
        bf16x8 bfr = *(const bf16x8*)(projw + (ncol0 + nt * 16 + l15) * 256 + k0 + quad * 8);
        #pragma unroll
        for (int mt = 0; mt < 4; ++mt)
          acc[mt][nt] = __builtin_amdgcn_mfma_f32_16x16x32_bf16(afr[mt], bfr, acc[mt][nt], 0, 0, 0);
      }
    }
    #pragma unroll
    for (int nt = 0; nt < 2; ++nt) {
      const int col = ncol0 + nt * 16 + l15;
      const float pb = proj_b[col];
      #pragma unroll
      for (int mt = 0; mt < 4; ++mt) {
        #pragma unroll
        for (int r = 0; r < 4; ++r) {
          const int tok = mt * 16 + quad * 4 + r;
          const int rw = tok >> 3, cw = tok & 7;
          const int gr = (wr * 8 + rw + 4) & 127;
          const int gc = (wc * 8 + cw + 4) & 127;
          out[((size_t)b * 16384 + gr * 128 + gc) * 256 + col] = acc[mt][nt][r] + pb;
        }
      }
    }
  }
}

// ---------------- launch ----------------

extern "C" void kernel_launch(void* const* d_in, const int* in_sizes, int n_in,
                              void* d_out, int out_size, void* d_ws, size_t ws_size,
                              hipStream_t stream) {
  const float* x           = (const float*)d_in[0];
  const float* qkv_w       = (const float*)d_in[1];
  const float* q_bias      = (const float*)d_in[2];
  const float* v_bias      = (const float*)d_in[3];
  const float* logit_scale = (const float*)d_in[4];
  const float* cpb_w1      = (const float*)d_in[5];
  const float* cpb_b1      = (const float*)d_in[6];
  const float* cpb_w2      = (const float*)d_in[7];
  const float* proj_w      = (const float*)d_in[8];
  const float* proj_b      = (const float*)d_in[9];
  unsigned char* ws = (unsigned char*)d_ws;
  float* out = (float*)d_out;

  prep_weights<<<768, 256, 0, stream>>>(qkv_w, q_bias, v_bias, logit_scale, proj_w, ws);
  prep_cpb<<<225, 512, 0, stream>>>(cpb_w1, cpb_b1, cpb_w2, ws);
  prep_bias<<<128, 256, 0, stream>>>(ws);

  swin_main<<<2048, 512, SMEM_BYTES, stream>>>(x, ws, out, proj_b);
}